// Round 9
// baseline (377.408 us; speedup 1.0000x reference)
//
#include <hip/hip_runtime.h>
#include <hip/hip_cooperative_groups.h>

namespace cg = cooperative_groups;

#define NN 50000
#define NE 800000
#define NR 8
#define DIN 128
#define DOUT 128
#define NH 8

#define NB_SCAN ((NN + 255) / 256)  // 196

typedef __attribute__((ext_vector_type(8))) short bf16x8;
typedef __attribute__((ext_vector_type(4))) float f32x4;

// ---------- helpers ----------
__device__ __forceinline__ unsigned short f2bf(float f) {
  unsigned u = __float_as_uint(f);
  unsigned r = (u + 0x7FFFu + ((u >> 16) & 1u)) >> 16;
  return (unsigned short)r;
}
__device__ __forceinline__ float bf2f(unsigned short b) {
  return __uint_as_float(((unsigned)b) << 16);
}

// ---------- kernel A (cooperative): prep_fcf + deg/cursor init + hist +
//            3-phase scan + CSR scatter, all in one launch ----------
__global__ __launch_bounds__(256) void build_csr(
    const float* __restrict__ fc, const float* __restrict__ attn,
    unsigned short* __restrict__ fcf, const int* __restrict__ src,
    const int* __restrict__ dst, const int* __restrict__ et,
    int* __restrict__ deg, int* __restrict__ cursor,
    int* __restrict__ row_start, int* __restrict__ bsum,
    int* __restrict__ bbase, unsigned* __restrict__ sidx) {
  cg::grid_group grid = cg::this_grid();
  const int tid = blockIdx.x * 256 + threadIdx.x;
  const int nth = gridDim.x * 256;  // 196*256 = 50176

  // ---- phase 0: zero deg/cursor + pack B-ext fragments (independent) ----
  for (int i = tid; i < NN; i += nth) {
    deg[i] = 0;
    cursor[i] = 0;
  }
  for (int idx = tid; idx < NR * DIN * 144; idx += nth) {
    int r = idx / (DIN * 144);
    int rem2 = idx - r * (DIN * 144);
    int k = rem2 / 144;
    int j = rem2 - k * 144;
    float v;
    if (j < DOUT) {
      v = fc[((size_t)r * DIN + k) * DOUT + j];
    } else {
      int cc = j - DOUT;  // 0..15
      int hh = cc & 7, p = cc >> 3;
      const float* fr = fc + ((size_t)r * DIN + k) * DOUT + hh * 16;
      const float* ar = attn + ((size_t)r * NH + hh) * 32 + p * 16;
      v = 0.f;
#pragma unroll
      for (int d = 0; d < 16; ++d) v += fr[d] * ar[d];
    }
    int t = j >> 4, c = j & 15, ks = k >> 5, gg = (k >> 3) & 3, i = k & 7;
    fcf[((((size_t)r * 9 + t) * 4 + ks) * 4 + gg) * 128 + c * 8 + i] = f2bf(v);
  }
  grid.sync();

  // ---- phase 1: degree histogram ----
  for (int e = tid; e < NE; e += nth) atomicAdd(&deg[dst[e]], 1);
  grid.sync();

  // ---- phase 2a: per-block partial sums (grid == NB_SCAN blocks) ----
  {
    __shared__ int ws_[4];
    int gi = blockIdx.x * 256 + threadIdx.x;
    int v = (gi < NN) ? deg[gi] : 0;
#pragma unroll
    for (int m = 1; m < 64; m <<= 1) v += __shfl_xor(v, m);
    if ((threadIdx.x & 63) == 0) ws_[threadIdx.x >> 6] = v;
    __syncthreads();
    if (threadIdx.x == 0) bsum[blockIdx.x] = ws_[0] + ws_[1] + ws_[2] + ws_[3];
  }
  grid.sync();

  // ---- phase 2b: block 0 scans the partials ----
  if (blockIdx.x == 0) {
    __shared__ int part[256];
    int t = threadIdx.x;
    part[t] = (t < NB_SCAN) ? bsum[t] : 0;
    __syncthreads();
    for (int off = 1; off < 256; off <<= 1) {
      int v = (t >= off) ? part[t - off] : 0;
      __syncthreads();
      part[t] += v;
      __syncthreads();
    }
    if (t < NB_SCAN) bbase[t] = (t == 0) ? 0 : part[t - 1];
    if (t == 0) row_start[NN] = NE;
  }
  grid.sync();

  // ---- phase 2c: block-local scan + base -> row_start ----
  {
    __shared__ int part[256];
    int t = threadIdx.x;
    int gi = blockIdx.x * 256 + t;
    int v = (gi < NN) ? deg[gi] : 0;
    part[t] = v;
    __syncthreads();
    for (int off = 1; off < 256; off <<= 1) {
      int x = (t >= off) ? part[t - off] : 0;
      __syncthreads();
      part[t] += x;
      __syncthreads();
    }
    if (gi < NN) row_start[gi] = bbase[blockIdx.x] + part[t] - v;
  }
  grid.sync();

  // ---- phase 3: scatter CSR permutation (4 B/edge) ----
  for (int e = tid; e < NE; e += nth) {
    int d = dst[e];
    int pos = row_start[d] + atomicAdd(&cursor[d], 1);
    sidx[pos] = (unsigned)src[e] | ((unsigned)et[e] << 16);
  }
}

// ---------- kernel B: MFMA GEMM, 4 relations per block, LDS-staged z stores ---
__global__ __launch_bounds__(256) void gemm_mfma(
    const float* __restrict__ h, const unsigned short* __restrict__ fcf,
    unsigned short* __restrict__ z, unsigned short* __restrict__ s_buf) {
  const int n0 = blockIdx.x * 64;
  const int rr0 = blockIdx.y * 4;
  const int w = threadIdx.x >> 6;
  const int lane = threadIdx.x & 63;
  const int g = lane >> 4, c = lane & 15;
  const int nbase = n0 + w * 16;

  __shared__ unsigned short zst[4][16][130];

  int arow = nbase + c;
  if (arow > NN - 1) arow = NN - 1;
  const float* ha = h + (size_t)arow * DIN + g * 8;
  bf16x8 af[4];
#pragma unroll
  for (int ks = 0; ks < 4; ++ks) {
    float4 v0 = *(const float4*)(ha + ks * 32);
    float4 v1 = *(const float4*)(ha + ks * 32 + 4);
    bf16x8 a;
    a[0] = (short)f2bf(v0.x); a[1] = (short)f2bf(v0.y);
    a[2] = (short)f2bf(v0.z); a[3] = (short)f2bf(v0.w);
    a[4] = (short)f2bf(v1.x); a[5] = (short)f2bf(v1.y);
    a[6] = (short)f2bf(v1.z); a[7] = (short)f2bf(v1.w);
    af[ks] = a;
  }

  const int node = nbase + c;

  for (int ri = 0; ri < 4; ++ri) {
    const int r = rr0 + ri;
    const unsigned short* fb = fcf + ((size_t)r * 36 * 64 + lane) * 8;
    f32x4 acc[9];
#pragma unroll
    for (int t = 0; t < 9; ++t) acc[t] = (f32x4){0.f, 0.f, 0.f, 0.f};

#pragma unroll
    for (int ks = 0; ks < 4; ++ks)
#pragma unroll
      for (int t = 0; t < 9; ++t) {
        bf16x8 bf = *(const bf16x8*)(fb + (size_t)(t * 4 + ks) * 512);
        acc[t] = __builtin_amdgcn_mfma_f32_16x16x32_bf16(bf, af[ks], acc[t], 0, 0, 0);
      }

#pragma unroll
    for (int t = 0; t < 8; ++t) {
      ushort4 wv;
      wv.x = f2bf(acc[t][0]); wv.y = f2bf(acc[t][1]);
      wv.z = f2bf(acc[t][2]); wv.w = f2bf(acc[t][3]);
      *(ushort4*)&zst[w][c][t * 16 + g * 4] = wv;
    }
    __builtin_amdgcn_s_waitcnt(0);  // lgkmcnt(0)
    unsigned short* zb = z + ((size_t)r * NN + nbase) * DOUT;
#pragma unroll
    for (int p = 0; p < 4; ++p) {
      int row = 4 * p + (lane >> 4);
      if (nbase + row < NN) {
        bf16x8 v = *(const bf16x8*)&zst[w][row][(lane & 15) * 8];
        *(bf16x8*)(zb + row * DOUT + (lane & 15) * 8) = v;
      }
    }

    if (node < NN) {
      ushort4 sv;
      sv.x = f2bf(acc[8][0]); sv.y = f2bf(acc[8][1]);
      sv.z = f2bf(acc[8][2]); sv.w = f2bf(acc[8][3]);
      *(ushort4*)&s_buf[((size_t)r * NN + node) * 16 + g * 4] = sv;
    }
  }
}

// ---------- kernel C: online-softmax gather-accumulate (1 wave/node) ----------
__global__ __launch_bounds__(256) void node_accum(
    const int* __restrict__ row_start, const unsigned* __restrict__ sidx,
    const unsigned short* __restrict__ s_buf, const unsigned short* __restrict__ z,
    float* __restrict__ out) {
  int wave = threadIdx.x >> 6;
  int lane = threadIdx.x & 63;
  int n = blockIdx.x * 4 + wave;
  if (n >= NN) return;
  int b0 = row_start[n];
  int deg = row_start[n + 1] - b0;

  int hl = lane & 7;    // head for score lanes
  int jg = lane >> 3;   // edge slot (0..7)
  int c16 = lane & 15;  // output col-block
  int e4 = lane >> 4;   // edge-subgroup for gather
  int hh16 = c16 >> 1;  // head of this lane's output cols

  float srn[8];
#pragma unroll
  for (int r = 0; r < 8; ++r)
    srn[r] = bf2f(s_buf[((size_t)r * NN + n) * 16 + 8 + hl]);

  float m = -INFINITY;
  float den = 0.f;
  float acc[8] = {0.f, 0.f, 0.f, 0.f, 0.f, 0.f, 0.f, 0.f};

  for (int cch = 0; cch < deg; cch += 8) {
    int j = cch + jg;
    int rem = min(8, deg - cch);
    float ev = -INFINITY;
    unsigned pj = 0;
    if (j < deg) {
      pj = sidx[b0 + j];
      unsigned s = pj & 0xFFFFu, r = pj >> 16;
      float sl = bf2f(s_buf[((size_t)r * NN + s) * 16 + hl]);
      float x = sl + srn[r];
      ev = x > 0.f ? x : 0.01f * x;
    }
    float cm = ev;
    cm = fmaxf(cm, __shfl_xor(cm, 8));
    cm = fmaxf(cm, __shfl_xor(cm, 16));
    cm = fmaxf(cm, __shfl_xor(cm, 32));
    float newm = fmaxf(m, cm);
    float scale = __expf(m - newm);
    float ex = __expf(ev - newm);
    float sumex = ex;
    sumex += __shfl_xor(sumex, 8);
    sumex += __shfl_xor(sumex, 16);
    sumex += __shfl_xor(sumex, 32);
    den = den * scale + sumex;
    m = newm;
    float sc_acc = __shfl(scale, hh16);
#pragma unroll
    for (int i = 0; i < 8; ++i) acc[i] *= sc_acc;
#pragma unroll
    for (int half = 0; half < 2; ++half) {
      if (half * 4 >= rem) break;
      int o = half * 4 + e4;
      float exb = __shfl(ex, (o << 3) | hh16);
      unsigned p = __shfl(pj, o << 3);
      unsigned sr_ = p & 0xFFFFu;
      unsigned rr = p >> 16;
      bf16x8 v = *(const bf16x8*)&z[(((size_t)rr * NN + sr_) << 7) + c16 * 8];
#pragma unroll
      for (int i = 0; i < 8; ++i)
        acc[i] += exb * bf2f((unsigned short)v[i]);
    }
  }
#pragma unroll
  for (int i = 0; i < 8; ++i) {
    acc[i] += __shfl_xor(acc[i], 16);
    acc[i] += __shfl_xor(acc[i], 32);
  }
  float deno = __shfl(den, hh16);
  float inv = 1.0f / fmaxf(deno, 1e-9f);
  if (lane < 16) {
    float* ob = out + ((size_t)n << 7) + lane * 8;
    *(float4*)ob = make_float4(acc[0] * inv, acc[1] * inv, acc[2] * inv, acc[3] * inv);
    *(float4*)(ob + 4) = make_float4(acc[4] * inv, acc[5] * inv, acc[6] * inv, acc[7] * inv);
  }
}

extern "C" void kernel_launch(void* const* d_in, const int* in_sizes, int n_in,
                              void* d_out, int out_size, void* d_ws, size_t ws_size,
                              hipStream_t stream) {
  const float* h = (const float*)d_in[0];
  const float* fc = (const float*)d_in[1];
  const float* attn = (const float*)d_in[2];
  const int* src = (const int*)d_in[3];
  const int* dst = (const int*)d_in[4];
  const int* et = (const int*)d_in[5];
  float* out = (float*)d_out;

  // workspace layout (16B-aligned chunks first)
  char* wsb = (char*)d_ws;
  size_t off = 0;
  unsigned short* z = (unsigned short*)(wsb + off);    off += (size_t)NR * NN * DOUT * 2;      // 102.4 MB
  unsigned short* s_buf = (unsigned short*)(wsb + off);off += (size_t)NR * NN * 16 * 2;        // 12.8 MB
  unsigned* sidx = (unsigned*)(wsb + off);             off += (size_t)NE * 4;                  // 3.2 MB
  unsigned short* fcf = (unsigned short*)(wsb + off);  off += (size_t)NR * 9 * 4 * 4 * 128 * 2;// 0.3 MB
  int* deg = (int*)(wsb + off);                        off += (size_t)NN * 4;
  int* row_start = (int*)(wsb + off);                  off += (size_t)(NN + 1) * 4;
  int* cursor = (int*)(wsb + off);                     off += (size_t)NN * 4;
  int* bsum = (int*)(wsb + off);                       off += (size_t)NB_SCAN * 4;
  int* bbase = (int*)(wsb + off);                      off += (size_t)NB_SCAN * 4;

  // ---- dispatch 1: cooperative CSR build + weight prep ----
  void* args[] = {(void*)&fc,  (void*)&attn,   (void*)&fcf,    (void*)&src,
                  (void*)&dst, (void*)&et,     (void*)&deg,    (void*)&cursor,
                  (void*)&row_start, (void*)&bsum, (void*)&bbase, (void*)&sidx};
  hipLaunchCooperativeKernel((void*)build_csr, dim3(NB_SCAN), dim3(256), args, 0,
                             stream);

  // ---- dispatch 2: projection GEMM ----
  dim3 ggrid((NN + 63) / 64, 2);
  gemm_mfma<<<ggrid, 256, 0, stream>>>(h, fcf, z, s_buf);

  // ---- dispatch 3: per-node softmax + gather ----
  node_accum<<<(NN + 3) / 4, 256, 0, stream>>>(row_start, sidx, s_buf, z, out);
}